// Round 6
// baseline (160.949 us; speedup 1.0000x reference)
//
#include <hip/hip_runtime.h>

// SSIM (B=16, C=3, H=W=512, fp32) -> scalar mean.
// v13: ringless streaming vertical pass.
//  - v12 post-mortem: VGPR_Count=40 with a 48-reg ring and zero scratch =>
//    compiler shuttles the ring through AGPRs (VALU copies, no memory). The
//    ring saves L2-hit re-reads that are nearly free (inputs L3-resident).
//  - v13 deletes the ring: per 2-row step, stream the 12 contributing rows
//    (v2f per img) straight into the 8 vertical accumulators. Same vertical
//    FMA count (124 v2f-ops/step), no ring shifts, no AGPR traffic.
//    Natural liveness ~35-55 VGPR -> (256,6) cap 85 is safe; grid 1536 =
//    6 blocks/CU -> entire grid co-resident, 24 waves/CU.
//  - Extra global reads (24/step vs 4) are L2/L3-served: ~590 MB logical
//    ~= 13 TB/s << 34.5 TB/s L2 ceiling; HBM FETCH stays ~100 MB.
//  - LDS layout unchanged (proven in v11/v12: conflicts 1.58M -> 4.6K):
//    8 scalar plane-row regions (4 planes x 2 rows), 528 dwords, halo 6/6.
//  - g[] in SGPRs via readfirstlane; single atomicAdd per block.

typedef float v2f __attribute__((ext_vector_type(2)));

#define IMG_H 512
#define IMG_W 512
#define N_IMG 48                    // B*C
#define WS 11
#define PAD 5
#define CHUNK 16                    // output rows per block
#define NCHUNK (IMG_H / CHUNK)      // 32
#define REG_DW 528                  // dwords per plane-row region (524 used)
#define REG_B (REG_DW * 4)          // 2112 bytes
#define NREG 8                      // 4 planes x 2 rows
#define INV_NPX (1.0f / (48.0f * 512.0f * 512.0f))

__device__ __forceinline__ v2f vfma(v2f a, v2f b, v2f c) {
    return __builtin_elementwise_fma(a, b, c);
}
__device__ __forceinline__ float uni(float x) {   // force wave-uniform -> SGPR
    return __int_as_float(__builtin_amdgcn_readfirstlane(__float_as_int(x)));
}

__global__ __launch_bounds__(256, 6) void ssim_partial_kernel(
    const float* __restrict__ img1,
    const float* __restrict__ img2,
    const float* __restrict__ window,
    float* __restrict__ out)
{
    __shared__ __align__(16) char lds[NREG * REG_B];   // 16896 B
    __shared__ float wred[4];

    const int tid = threadIdx.x;
    const int bc  = blockIdx.x;              // image*channel 0..47
    const int r0  = blockIdx.y * CHUNK;
    const int c0  = tid * 2;                 // thread owns cols c0, c0+1

    // 1-D gaussian from window row 5 (w2d[5][j] = g5*g[j]); hoist to SGPRs.
    float g[WS];
    {
        const float g5  = sqrtf(window[5 * WS + 5]);
        const float inv = 1.0f / g5;
#pragma unroll
        for (int j = 0; j < WS; ++j) g[j] = uni(window[5 * WS + j] * inv);
    }
    const float C1v = 0.01f * 0.01f;
    const float C2v = 0.03f * 0.03f;

    const float* __restrict__ p1 = img1 + (size_t)bc * (IMG_H * IMG_W) + c0;
    const float* __restrict__ p2 = img2 + (size_t)bc * (IMG_H * IMG_W) + c0;

    // zero halo: dword idx 0..5 (cols -6..-1) and 518..523 (cols 512..517)
    if (tid < 96) {
        const int rg = tid / 12, h = tid % 12;
        const int idx = (h < 6) ? h : (512 + h);
        *(float*)(lds + rg * REG_B + idx * 4) = 0.0f;
    }
    __syncthreads();

    // LDS addressing: dword index of global col c is c+6 within a region.
    char*       wb = lds + (c0 + 6) * 4;     // write base (8B aligned)
    const char* rb = lds + c0 * 4;           // read base: col c0-6 (8B aligned)

    float acc = 0.0f;

#pragma unroll 1
    for (int step = 0; step < CHUNK / 2; ++step) {
        const int R = r0 + step * 2;           // output rows R, R+1

        // ---- streaming vertical pass: rows R-5 .. R+6 ----
        // va[p][k]: p = {mu1, mu2, S=x1^2+x2^2, P=x1*x2}, k = output row
        v2f va[4][2];
#pragma unroll
        for (int p = 0; p < 4; ++p)
#pragma unroll
            for (int k = 0; k < 2; ++k) va[p][k] = (v2f)(0.0f);

#pragma unroll
        for (int i = 0; i < 12; ++i) {
            const int rr = R - PAD + i;
            v2f X1 = (v2f)(0.0f), X2 = (v2f)(0.0f);
            if (rr >= 0 && rr < IMG_H) {       // uniform branch
                X1 = *(const v2f*)(p1 + rr * IMG_W);
                X2 = *(const v2f*)(p2 + rr * IMG_W);
            }
            const v2f S = vfma(X1, X1, X2 * X2);
            const v2f P = X1 * X2;
            if (i <= 10) {                     // k=0 tap i
                const v2f w = (v2f)(g[i]);
                va[0][0] = vfma(w, X1, va[0][0]);
                va[1][0] = vfma(w, X2, va[1][0]);
                va[2][0] = vfma(w, S,  va[2][0]);
                va[3][0] = vfma(w, P,  va[3][0]);
            }
            if (i >= 1) {                      // k=1 tap i-1
                const v2f w = (v2f)(g[i - 1]);
                va[0][1] = vfma(w, X1, va[0][1]);
                va[1][1] = vfma(w, X2, va[1][1]);
                va[2][1] = vfma(w, S,  va[2][1]);
                va[3][1] = vfma(w, P,  va[3][1]);
            }
        }
#pragma unroll
        for (int p = 0; p < 4; ++p)
#pragma unroll
            for (int k = 0; k < 2; ++k)
                *(v2f*)(wb + (p * 2 + k) * REG_B) = va[p][k];
        __syncthreads();

        // ---- horizontal conv + SSIM, per output row k ----
#pragma unroll
        for (int k = 0; k < 2; ++k) {
            v2f h[4];
#pragma unroll
            for (int p = 0; p < 4; ++p) {
                const char* base = rb + (p * 2 + k) * REG_B;
                float hx = 0.0f, hy = 0.0f;
                // stream 7 x ds_read_b64: t = {s[2j], s[2j+1]}, s[n] = col c0-6+n
                // hx (col c0):   tap i uses s[i+1]; hy (col c0+1): s[i+2]
#pragma unroll
                for (int j = 0; j < 7; ++j) {
                    const v2f t = *(const v2f*)(base + j * 8);
                    const int ix0 = 2 * j - 1;   // hx tap for t.x
                    const int iy0 = 2 * j - 2;   // hy tap for t.x
                    if (ix0 >= 0 && ix0 <= 10) hx = fmaf(g[ix0], t.x, hx);
                    if (iy0 >= 0 && iy0 <= 10) hy = fmaf(g[iy0], t.x, hy);
                    const int ix1 = 2 * j;       // hx tap for t.y
                    const int iy1 = 2 * j - 1;   // hy tap for t.y
                    if (ix1 >= 0 && ix1 <= 10) hx = fmaf(g[ix1], t.y, hx);
                    if (iy1 >= 0 && iy1 <= 10) hy = fmaf(g[iy1], t.y, hy);
                }
                h[p] = (v2f){hx, hy};
            }
            const v2f mu1 = h[0], mu2 = h[1];
            const v2f mu1s = mu1 * mu1;
            const v2f mu2s = mu2 * mu2;
            const v2f mu12 = mu1 * mu2;
            const v2f sgs  = h[2] - mu1s - mu2s;       // sigma1^2 + sigma2^2
            const v2f sg12 = h[3] - mu12;
            const v2f num  = (2.f * mu12 + (v2f)(C1v)) * (2.f * sg12 + (v2f)(C2v));
            const v2f den  = (mu1s + mu2s + (v2f)(C1v)) * (sgs + (v2f)(C2v));
            v2f r = {__builtin_amdgcn_rcpf(den.x), __builtin_amdgcn_rcpf(den.y)};
            r = r * vfma(-den, r, (v2f)(2.0f));        // Newton -> ~1 ulp
            acc = fmaf(num.x, r.x, acc);
            acc = fmaf(num.y, r.y, acc);
        }
        __syncthreads();                               // before LDS overwrite
    }

    // block reduction -> single atomic per block (pre-scaled by 1/Npx)
#pragma unroll
    for (int off = 32; off > 0; off >>= 1)
        acc += __shfl_down(acc, off);
    if ((tid & 63) == 0) wred[tid >> 6] = acc;
    __syncthreads();
    if (tid == 0) {
        const float s = (wred[0] + wred[1]) + (wred[2] + wred[3]);
        atomicAdd(out, s * INV_NPX);
    }
}

extern "C" void kernel_launch(void* const* d_in, const int* in_sizes, int n_in,
                              void* d_out, int out_size, void* d_ws, size_t ws_size,
                              hipStream_t stream) {
    const float* img1   = (const float*)d_in[0];
    const float* img2   = (const float*)d_in[1];
    const float* window = (const float*)d_in[2];
    float* out = (float*)d_out;

    hipMemsetAsync(out, 0, sizeof(float), stream);   // graph-capturable
    dim3 grid(N_IMG, NCHUNK);
    ssim_partial_kernel<<<grid, 256, 0, stream>>>(img1, img2, window, out);
}

// Round 7
// 147.260 us; speedup vs baseline: 1.0930x; 1.0930x over previous
//
#include <hip/hip_runtime.h>

// SSIM (B=16, C=3, H=W=512, fp32) -> scalar mean.
// v14: v12 structure (register ring + scalar plane-row LDS), single change:
//      __launch_bounds__(256,6).
//  - v13 post-mortem: ringless streaming tripled HBM FETCH (79->210 MB; the
//    4 MB per-XCD L2 evicts rows between re-uses) and regressed 60->88 us.
//    Ring restored.
//  - v12 measured: VALU-issue ~28 us (floor ~25), LDS pipe ~26 us -- both
//    near-floor and overlappable; gap is residency/tail. Grid 1536 = 6*256
//    exactly -> at 6 blocks/CU the whole grid is co-resident, no tail,
//    24 waves/CU.
//  - v11 spilled at cap 85 WITH full unroll; v12 showed unroll-1 +
//    AGPR-shuttling keeps scratch at zero (VGPR=40, WRITE=48 KB). Betting
//    the same holds at cap 85. Falsifier: WRITE_SIZE >10 MB -> revert (256,5).
//  - LDS layout (proven: conflicts 1.58M -> 4.6K): 8 scalar plane-row
//    regions (4 planes x 2 rows), 528 dwords each, halo 6/6; reads/writes
//    lane-stride-2-dword = 2-way aliasing = free.
//  - g[] in SGPRs via readfirstlane; single atomicAdd per block.

typedef float v2f __attribute__((ext_vector_type(2)));

#define IMG_H 512
#define IMG_W 512
#define N_IMG 48                    // B*C
#define WS 11
#define PAD 5
#define CHUNK 16                    // output rows per block
#define NCHUNK (IMG_H / CHUNK)      // 32
#define RING 12                     // rows held in registers
#define REG_DW 528                  // dwords per plane-row region (524 used)
#define REG_B (REG_DW * 4)          // 2112 bytes
#define NREG 8                      // 4 planes x 2 rows
#define INV_NPX (1.0f / (48.0f * 512.0f * 512.0f))

__device__ __forceinline__ v2f vfma(v2f a, v2f b, v2f c) {
    return __builtin_elementwise_fma(a, b, c);
}
__device__ __forceinline__ float uni(float x) {   // force wave-uniform -> SGPR
    return __int_as_float(__builtin_amdgcn_readfirstlane(__float_as_int(x)));
}

__global__ __launch_bounds__(256, 6) void ssim_partial_kernel(
    const float* __restrict__ img1,
    const float* __restrict__ img2,
    const float* __restrict__ window,
    float* __restrict__ out)
{
    __shared__ __align__(16) char lds[NREG * REG_B];   // 16896 B
    __shared__ float wred[4];

    const int tid = threadIdx.x;
    const int bc  = blockIdx.x;              // image*channel 0..47
    const int r0  = blockIdx.y * CHUNK;
    const int c0  = tid * 2;                 // thread owns cols c0, c0+1

    // 1-D gaussian from window row 5 (w2d[5][j] = g5*g[j]); hoist to SGPRs.
    float g[WS];
    {
        const float g5  = sqrtf(window[5 * WS + 5]);
        const float inv = 1.0f / g5;
#pragma unroll
        for (int j = 0; j < WS; ++j) g[j] = uni(window[5 * WS + j] * inv);
    }
    const float C1v = 0.01f * 0.01f;
    const float C2v = 0.03f * 0.03f;

    const float* __restrict__ p1 = img1 + (size_t)bc * (IMG_H * IMG_W);
    const float* __restrict__ p2 = img2 + (size_t)bc * (IMG_H * IMG_W);

    // zero halo: dword idx 0..5 (cols -6..-1) and 518..523 (cols 512..517)
    if (tid < 96) {
        const int rg = tid / 12, h = tid % 12;
        const int idx = (h < 6) ? h : (512 + h);
        *(float*)(lds + rg * REG_B + idx * 4) = 0.0f;
    }
    __syncthreads();

    // LDS addressing: dword index of global col c is c+6 within a region.
    char*       wb = lds + (c0 + 6) * 4;     // write base (8B aligned)
    const char* rb = lds + c0 * 4;           // read base: col c0-6 (8B aligned)

    // register ring: slot i holds row R-5+i at step base R
    v2f rx1[RING], rx2[RING];
#pragma unroll
    for (int i = 0; i < RING; ++i) { rx1[i] = (v2f)(0.0f); rx2[i] = (v2f)(0.0f); }

    // warm-up: slots 2..11 <- rows r0-5 .. r0+4
#pragma unroll
    for (int i = 0; i < 10; ++i) {
        const int rr = r0 - PAD + i;
        v2f u1 = (v2f)(0.0f), u2 = (v2f)(0.0f);
        if (rr >= 0 && rr < IMG_H) {               // uniform branch
            u1 = *(const v2f*)(p1 + rr * IMG_W + c0);
            u2 = *(const v2f*)(p2 + rr * IMG_W + c0);
        }
        rx1[2 + i] = u1; rx2[2 + i] = u2;
    }

    float acc = 0.0f;

#pragma unroll 1
    for (int step = 0; step < CHUNK / 2; ++step) {
        const int R = r0 + step * 2;           // output rows R, R+1

        // shift ring by 2 (real v_movs; indices stay compile-time constant)
#pragma unroll
        for (int i = 0; i < RING - 2; ++i) { rx1[i] = rx1[i + 2]; rx2[i] = rx2[i + 2]; }
        // load rows R+5, R+6 -> slots 10, 11
#pragma unroll
        for (int j = 0; j < 2; ++j) {
            const int rr = R + PAD + j;
            v2f u1 = (v2f)(0.0f), u2 = (v2f)(0.0f);
            if (rr < IMG_H) {                  // uniform branch
                u1 = *(const v2f*)(p1 + rr * IMG_W + c0);
                u2 = *(const v2f*)(p2 + rr * IMG_W + c0);
            }
            rx1[10 + j] = u1; rx2[10 + j] = u2;
        }

        // ---- vertical pass A: mu1, mu2 (planes 0,1), rows k=0,1 ----
        {
            v2f a0[2] = {(v2f)(0.0f), (v2f)(0.0f)};
            v2f a1[2] = {(v2f)(0.0f), (v2f)(0.0f)};
#pragma unroll
            for (int k = 0; k < 2; ++k)
#pragma unroll
                for (int i = 0; i < WS; ++i) {
                    const v2f w = (v2f)(g[i]);
                    a0[k] = vfma(w, rx1[i + k], a0[k]);
                    a1[k] = vfma(w, rx2[i + k], a1[k]);
                }
#pragma unroll
            for (int k = 0; k < 2; ++k) {
                *(v2f*)(wb + (0 + k) * REG_B) = a0[k];   // plane0 row k
                *(v2f*)(wb + (2 + k) * REG_B) = a1[k];   // plane1 row k
            }
        }
        // ---- vertical pass B: S = x1^2+x2^2, P = x1*x2 (planes 2,3) ----
        {
            v2f b0[2] = {(v2f)(0.0f), (v2f)(0.0f)};
            v2f b1[2] = {(v2f)(0.0f), (v2f)(0.0f)};
#pragma unroll
            for (int u = 0; u < RING; ++u) {
                const v2f X1 = rx1[u], X2 = rx2[u];
                const v2f S = vfma(X1, X1, X2 * X2);
                const v2f P = X1 * X2;
                if (u <= 10) {                          // k=0 tap i=u
                    b0[0] = vfma((v2f)(g[u]), S, b0[0]);
                    b1[0] = vfma((v2f)(g[u]), P, b1[0]);
                }
                if (u >= 1) {                           // k=1 tap i=u-1
                    b0[1] = vfma((v2f)(g[u - 1]), S, b0[1]);
                    b1[1] = vfma((v2f)(g[u - 1]), P, b1[1]);
                }
            }
#pragma unroll
            for (int k = 0; k < 2; ++k) {
                *(v2f*)(wb + (4 + k) * REG_B) = b0[k];   // plane2 row k
                *(v2f*)(wb + (6 + k) * REG_B) = b1[k];   // plane3 row k
            }
        }
        __syncthreads();

        // ---- horizontal conv + SSIM, per output row k ----
#pragma unroll
        for (int k = 0; k < 2; ++k) {
            v2f h[4];
#pragma unroll
            for (int p = 0; p < 4; ++p) {
                const char* base = rb + (p * 2 + k) * REG_B;
                float hx = 0.0f, hy = 0.0f;
                // stream 7 x ds_read_b64: t = {s[2j], s[2j+1]}, s[n] = col c0-6+n
                // hx (col c0):   tap i uses s[i+1]; hy (col c0+1): s[i+2]
#pragma unroll
                for (int j = 0; j < 7; ++j) {
                    const v2f t = *(const v2f*)(base + j * 8);
                    const int ix0 = 2 * j - 1;   // hx tap for t.x
                    const int iy0 = 2 * j - 2;   // hy tap for t.x
                    if (ix0 >= 0 && ix0 <= 10) hx = fmaf(g[ix0], t.x, hx);
                    if (iy0 >= 0 && iy0 <= 10) hy = fmaf(g[iy0], t.x, hy);
                    const int ix1 = 2 * j;       // hx tap for t.y
                    const int iy1 = 2 * j - 1;   // hy tap for t.y
                    if (ix1 >= 0 && ix1 <= 10) hx = fmaf(g[ix1], t.y, hx);
                    if (iy1 >= 0 && iy1 <= 10) hy = fmaf(g[iy1], t.y, hy);
                }
                h[p] = (v2f){hx, hy};
            }
            const v2f mu1 = h[0], mu2 = h[1];
            const v2f mu1s = mu1 * mu1;
            const v2f mu2s = mu2 * mu2;
            const v2f mu12 = mu1 * mu2;
            const v2f sgs  = h[2] - mu1s - mu2s;       // sigma1^2 + sigma2^2
            const v2f sg12 = h[3] - mu12;
            const v2f num  = (2.f * mu12 + (v2f)(C1v)) * (2.f * sg12 + (v2f)(C2v));
            const v2f den  = (mu1s + mu2s + (v2f)(C1v)) * (sgs + (v2f)(C2v));
            v2f r = {__builtin_amdgcn_rcpf(den.x), __builtin_amdgcn_rcpf(den.y)};
            r = r * vfma(-den, r, (v2f)(2.0f));        // Newton -> ~1 ulp
            acc = fmaf(num.x, r.x, acc);
            acc = fmaf(num.y, r.y, acc);
        }
        __syncthreads();                               // before LDS overwrite
    }

    // block reduction -> single atomic per block (pre-scaled by 1/Npx)
#pragma unroll
    for (int off = 32; off > 0; off >>= 1)
        acc += __shfl_down(acc, off);
    if ((tid & 63) == 0) wred[tid >> 6] = acc;
    __syncthreads();
    if (tid == 0) {
        const float s = (wred[0] + wred[1]) + (wred[2] + wred[3]);
        atomicAdd(out, s * INV_NPX);
    }
}

extern "C" void kernel_launch(void* const* d_in, const int* in_sizes, int n_in,
                              void* d_out, int out_size, void* d_ws, size_t ws_size,
                              hipStream_t stream) {
    const float* img1   = (const float*)d_in[0];
    const float* img2   = (const float*)d_in[1];
    const float* window = (const float*)d_in[2];
    float* out = (float*)d_out;

    hipMemsetAsync(out, 0, sizeof(float), stream);   // graph-capturable
    dim3 grid(N_IMG, NCHUNK);
    ssim_partial_kernel<<<grid, 256, 0, stream>>>(img1, img2, window, out);
}